// Round 8
// baseline (353.327 us; speedup 1.0000x reference)
//
#include <hip/hip_runtime.h>

#define IN_DIM 128
#define OUT_DIM 128
#define NUM_RELS 8

typedef unsigned short u16;
typedef u16 u16x8 __attribute__((ext_vector_type(8)));
typedef u16 u16x4 __attribute__((ext_vector_type(4)));
typedef __bf16 bf16x8 __attribute__((ext_vector_type(8)));
typedef float f32x4 __attribute__((ext_vector_type(4)));

__device__ __forceinline__ u16 f2bf(float f) {
    unsigned u = __float_as_uint(f);
    u += 0x7FFF + ((u >> 16) & 1);      // RNE
    return (u16)(u >> 16);
}
__device__ __forceinline__ float bf2f(u16 h) {
    return __uint_as_float((unsigned)h << 16);
}

// ---------- zero cursor + lookback state ----------
__global__ __launch_bounds__(256) void k_zero(int4* __restrict__ p, int n4)
{
    int i = blockIdx.x * 256 + threadIdx.x;
    if (i < n4) p[i] = make_int4(0, 0, 0, 0);
}

// ---------- prep: cast x -> bf16, build WbT [col][k] (k = rel*128+kin,
// k 1024..1151 = self-loop), (dst,rel) histogram (cursor pre-zeroed) ----------
__global__ __launch_bounds__(256) void k_prep(
    const float* __restrict__ x, const float* __restrict__ weight,
    const float* __restrict__ slw,
    const int* __restrict__ dst, const int* __restrict__ et,
    u16* __restrict__ xb, u16* __restrict__ WbT, int* __restrict__ cursor,
    int* __restrict__ row_ptr,
    int N, int E, int n8, int BA, int BB)
{
    const int b = blockIdx.x;
    const int tid = threadIdx.x;
    if (b == 0 && tid == 0) row_ptr[n8] = E;
    if (b < BA) {
        long i = ((long)b * 256 + tid) * 4;
        if (i < (long)N * 128) {
            float4 v = *(const float4*)(x + i);
            u16x4 o;
            o[0] = f2bf(v.x); o[1] = f2bf(v.y); o[2] = f2bf(v.z); o[3] = f2bf(v.w);
            *(u16x4*)(xb + i) = o;
        }
    } else if (b < BA + BB) {
        int i = ((b - BA) * 256 + tid) * 4;      // elem idx into WbT[128][1152]
        if (i < 128 * 1152) {
            const int col = i / 1152;
            const int kk  = i - col * 1152;
            u16x4 o;
            #pragma unroll
            for (int j = 0; j < 4; ++j) {
                const int kj = kk + j;
                const float f = (kj < 1024)
                    ? weight[((kj >> 7) << 14) + ((kj & 127) << 7) + col]
                    : slw[((kj - 1024) << 7) + col];
                o[j] = f2bf(f);
            }
            *(u16x4*)(WbT + i) = o;
        }
    } else {
        int e = (b - BA - BB) * 256 + tid;
        if (e < E) atomicAdd(&cursor[(dst[e] << 3) + et[e]], 1);
    }
}

// ---------- single-kernel scan: decoupled lookback [verified R5/R6] ----------
__global__ __launch_bounds__(512) void k_scan_lb(
    const int* __restrict__ deg, int* __restrict__ row_ptr,
    int* __restrict__ cursor, unsigned long long* __restrict__ part, int n)
{
    __shared__ int s[512];
    __shared__ int s_exc;
    const int c = blockIdx.x;
    const int t = threadIdx.x;
    const int base = (c << 12) + (t << 3);
    int v[8]; int sum = 0;
    #pragma unroll
    for (int j = 0; j < 8; ++j) {
        const int i = base + j;
        v[j] = (i < n) ? deg[i] : 0;
        sum += v[j];
    }
    s[t] = sum;
    __syncthreads();
    #pragma unroll
    for (int off = 1; off < 512; off <<= 1) {
        const int y = (t >= off) ? s[t - off] : 0;
        __syncthreads();
        s[t] += y;
        __syncthreads();
    }
    const int total = s[511];
    const int run = s[t] - sum;

    if (t == 0) {
        const unsigned long long st = (c == 0) ? 2ULL : 1ULL;
        __hip_atomic_store(&part[c], (st << 32) | (unsigned int)total,
                           __ATOMIC_RELAXED, __HIP_MEMORY_SCOPE_AGENT);
    }

    int exc = 0;
    if (c > 0 && t < 64) {
        int bj = c - 1;
        while (true) {
            const int idx = bj - t;
            unsigned long long w = 0;
            if (idx >= 0) {
                do {
                    w = __hip_atomic_load(&part[idx], __ATOMIC_RELAXED,
                                          __HIP_MEMORY_SCOPE_AGENT);
                } while ((w >> 32) == 0ULL);
            }
            const unsigned long long incmask =
                __ballot(idx >= 0 && (w >> 32) == 2ULL);
            const int Ls = incmask ? (__ffsll(incmask) - 1) : 64;
            unsigned int contrib =
                (idx >= 0 && t <= Ls) ? (unsigned int)(w & 0xffffffffULL) : 0u;
            #pragma unroll
            for (int o = 32; o >= 1; o >>= 1) contrib += __shfl_xor(contrib, o);
            exc += (int)contrib;
            if (Ls < 64) break;
            bj -= 64;
        }
        if (t == 0) {
            __hip_atomic_store(&part[c],
                (2ULL << 32) | (unsigned int)(exc + total),
                __ATOMIC_RELAXED, __HIP_MEMORY_SCOPE_AGENT);
            s_exc = exc;
        }
    } else if (t == 0) {
        s_exc = 0;
    }
    __syncthreads();
    exc = s_exc;
    int acc_ = exc + run;
    #pragma unroll
    for (int j = 0; j < 8; ++j) {
        const int i = base + j;
        if (i < n) { row_ptr[i] = acc_; cursor[i] = acc_; }
        acc_ += v[j];
    }
}

__global__ __launch_bounds__(256) void k_fill(
    const int* __restrict__ src, const int* __restrict__ dst,
    const int* __restrict__ et, int* __restrict__ cursor,
    int* __restrict__ packed, int E)
{
    int e = blockIdx.x * blockDim.x + threadIdx.x;
    if (e >= E) return;
    int pos = atomicAdd(&cursor[(dst[e] << 3) + et[e]], 1);
    packed[pos] = (et[e] << 17) | src[e];
}

// ---------- R7a resubmit: stand-alone gather/aggregate (R0-proven regime) ---
// one 16-lane group per node, ALL 9 rels in one pass (edges rel-sorted by
// the (dst,rel) CSR), 8 loads in flight/lane, fp32 accum + per-rel bf16
// flush into agg[N][1152] (110 MB -> L3-resident, consumed by k_gemm).
// No LDS, no barriers; launch_bounds(256,8) targets 64 VGPR / 32 waves/CU.
__global__ __launch_bounds__(256, 8) void k_gather(
    const u16* __restrict__ xb,      // [N][128] bf16
    const int* __restrict__ row_ptr, // [8N+1]
    const int* __restrict__ packed,  // [E]: (rel<<17)|src, grouped by (dst,rel)
    u16* __restrict__ agg,           // [>=N][1152] bf16 out
    int N)
{
    const int grp = threadIdx.x >> 4;          // 16 groups/block
    const int lo  = (threadIdx.x & 15) << 3;   // 8 bf16 (16 B) per lane
    const int gn  = blockIdx.x * 16 + grp;
    if (gn >= N) return;

    const int beg = row_ptr[gn << 3];
    const int end = row_ptr[(gn << 3) + 8];
    u16* arow = agg + (size_t)gn * 1152 + lo;

    float a0=0.f,a1=0.f,a2=0.f,a3=0.f,a4=0.f,a5=0.f,a6=0.f,a7=0.f;
    int cur = 0;

#define FLUSH_() { u16x8 o_; \
    o_[0]=f2bf(a0); o_[1]=f2bf(a1); o_[2]=f2bf(a2); o_[3]=f2bf(a3); \
    o_[4]=f2bf(a4); o_[5]=f2bf(a5); o_[6]=f2bf(a6); o_[7]=f2bf(a7); \
    *(u16x8*)(arow + (cur << 7)) = o_; \
    a0=0.f;a1=0.f;a2=0.f;a3=0.f;a4=0.f;a5=0.f;a6=0.f;a7=0.f; ++cur; }

#define PROC_(p_, v_) { const int r_ = (p_) >> 17; \
    while (cur < r_) { FLUSH_(); } \
    a0 += bf2f((v_)[0]); a1 += bf2f((v_)[1]); a2 += bf2f((v_)[2]); a3 += bf2f((v_)[3]); \
    a4 += bf2f((v_)[4]); a5 += bf2f((v_)[5]); a6 += bf2f((v_)[6]); a7 += bf2f((v_)[7]); }

    int k = beg;
    for (; k + 8 <= end; k += 8) {            // 8 independent loads in flight
        const int p0 = packed[k],     p1 = packed[k + 1];
        const int p2 = packed[k + 2], p3 = packed[k + 3];
        const int p4 = packed[k + 4], p5 = packed[k + 5];
        const int p6 = packed[k + 6], p7 = packed[k + 7];
        const u16x8 v0 = *(const u16x8*)(xb + ((size_t)(p0 & 0x1FFFF) << 7) + lo);
        const u16x8 v1 = *(const u16x8*)(xb + ((size_t)(p1 & 0x1FFFF) << 7) + lo);
        const u16x8 v2 = *(const u16x8*)(xb + ((size_t)(p2 & 0x1FFFF) << 7) + lo);
        const u16x8 v3 = *(const u16x8*)(xb + ((size_t)(p3 & 0x1FFFF) << 7) + lo);
        const u16x8 v4 = *(const u16x8*)(xb + ((size_t)(p4 & 0x1FFFF) << 7) + lo);
        const u16x8 v5 = *(const u16x8*)(xb + ((size_t)(p5 & 0x1FFFF) << 7) + lo);
        const u16x8 v6 = *(const u16x8*)(xb + ((size_t)(p6 & 0x1FFFF) << 7) + lo);
        const u16x8 v7 = *(const u16x8*)(xb + ((size_t)(p7 & 0x1FFFF) << 7) + lo);
        PROC_(p0, v0); PROC_(p1, v1); PROC_(p2, v2); PROC_(p3, v3);
        PROC_(p4, v4); PROC_(p5, v5); PROC_(p6, v6); PROC_(p7, v7);
    }
    for (; k + 4 <= end; k += 4) {
        const int p0 = packed[k],     p1 = packed[k + 1];
        const int p2 = packed[k + 2], p3 = packed[k + 3];
        const u16x8 v0 = *(const u16x8*)(xb + ((size_t)(p0 & 0x1FFFF) << 7) + lo);
        const u16x8 v1 = *(const u16x8*)(xb + ((size_t)(p1 & 0x1FFFF) << 7) + lo);
        const u16x8 v2 = *(const u16x8*)(xb + ((size_t)(p2 & 0x1FFFF) << 7) + lo);
        const u16x8 v3 = *(const u16x8*)(xb + ((size_t)(p3 & 0x1FFFF) << 7) + lo);
        PROC_(p0, v0); PROC_(p1, v1); PROC_(p2, v2); PROC_(p3, v3);
    }
    for (; k < end; ++k) {
        const int p = packed[k];
        const u16x8 v = *(const u16x8*)(xb + ((size_t)(p & 0x1FFFF) << 7) + lo);
        PROC_(p, v);
    }
    while (cur < 8) { FLUSH_(); }             // empty rels -> explicit zeros
#undef PROC_
#undef FLUSH_

    // self-loop slot (k 1024..1151) = xb row verbatim
    *(u16x8*)(arow + 1024) = *(const u16x8*)(xb + ((size_t)gn << 7) + lo);
}

// ---------- R7b: dense GEMM out[N x 128] = agg[N x 1152] @ WbT^T + bias,relu
// mfma_gemm2's proven access pattern: A-frags direct from global (L3-resident
// agg), B-frags 16-B vector loads from L2-hot WbT. 8 waves x 16 cols,
// 4 m-subtiles, K=1152. No LDS. Tail agg rows (>=N) read garbage but their
// outputs are masked.
__global__ __launch_bounds__(512, 6) void k_gemm(
    const u16* __restrict__ agg,     // [>=ntiles*64][1152] bf16
    const u16* __restrict__ WbT,     // [128][1152] bf16
    const float* __restrict__ bias,
    float* __restrict__ out, int N)
{
    const int tid = threadIdx.x;
    const int lane = tid & 63, wv = tid >> 6;
    const int q = lane >> 4, l = lane & 15;
    const int cbase = wv << 4;
    const int n0 = blockIdx.x * 64;
    const float bv = bias[cbase + l];

    const u16* Bp = WbT + (size_t)(cbase + l) * 1152 + (q << 3);
    const u16* Ap = agg + (size_t)(n0 + l) * 1152 + (q << 3);

    f32x4 acc[4] = {};
    #pragma unroll 4
    for (int kk = 0; kk < 36; ++kk) {
        const int ko = kk << 5;
        const bf16x8 b = __builtin_bit_cast(bf16x8, *(const u16x8*)(Bp + ko));
        #pragma unroll
        for (int mt = 0; mt < 4; ++mt) {
            const bf16x8 a = __builtin_bit_cast(
                bf16x8, *(const u16x8*)(Ap + (size_t)mt * 16 * 1152 + ko));
            acc[mt] = __builtin_amdgcn_mfma_f32_16x16x32_bf16(a, b, acc[mt], 0, 0, 0);
        }
    }

    // C layout: col = lane&15, row = q*4 + j (within 16-row tile)
    #pragma unroll
    for (int mt = 0; mt < 4; ++mt) {
        const int rbase = n0 + (mt << 4) + (q << 2);
        #pragma unroll
        for (int j = 0; j < 4; ++j) {
            const int row = rbase + j;
            if (row < N)
                out[(size_t)row * 128 + cbase + l] = fmaxf(acc[mt][j] + bv, 0.f);
        }
    }
}

// ---------- R6 fused kernel (fallback if agg buffer doesn't fit) ----------
#define NPB 64
#define LDK 392

__device__ __forceinline__ void gather8(
    u16* arow, const u16* __restrict__ xb, const int* __restrict__ packed,
    int beg, int end, int r0, int r1, int lo)
{
    float a[16];
    #pragma unroll
    for (int j = 0; j < 16; ++j) a[j] = 0.f;
    int cur = r0;

    auto flush = [&]() {
        u16x8 ol, oh;
        #pragma unroll
        for (int j = 0; j < 8; ++j) {
            ol[j] = f2bf(a[j]);     a[j] = 0.f;
            oh[j] = f2bf(a[8 + j]); a[8 + j] = 0.f;
        }
        u16* p = arow + ((cur - r0) << 7) + lo;
        *(u16x8*)p = ol;
        *(u16x8*)(p + 8) = oh;
        ++cur;
    };
    auto proc = [&](int p, const u16x8& vl, const u16x8& vh) {
        const int r_ = p >> 17;
        while (cur < r_) flush();
        #pragma unroll
        for (int j = 0; j < 8; ++j) {
            a[j]     += bf2f(vl[j]);
            a[8 + j] += bf2f(vh[j]);
        }
    };

    int k = beg;
    for (; k + 4 <= end; k += 4) {
        const int p0 = packed[k],     p1 = packed[k + 1];
        const int p2 = packed[k + 2], p3 = packed[k + 3];
        const u16* b0 = xb + ((size_t)(p0 & 0x1FFFF) << 7) + lo;
        const u16* b1 = xb + ((size_t)(p1 & 0x1FFFF) << 7) + lo;
        const u16* b2 = xb + ((size_t)(p2 & 0x1FFFF) << 7) + lo;
        const u16* b3 = xb + ((size_t)(p3 & 0x1FFFF) << 7) + lo;
        const u16x8 v0l = *(const u16x8*)b0, v0h = *(const u16x8*)(b0 + 8);
        const u16x8 v1l = *(const u16x8*)b1, v1h = *(const u16x8*)(b1 + 8);
        const u16x8 v2l = *(const u16x8*)b2, v2h = *(const u16x8*)(b2 + 8);
        const u16x8 v3l = *(const u16x8*)b3, v3h = *(const u16x8*)(b3 + 8);
        proc(p0, v0l, v0h); proc(p1, v1l, v1h);
        proc(p2, v2l, v2h); proc(p3, v3l, v3h);
    }
    for (; k < end; ++k) {
        const int p = packed[k];
        const u16* b = xb + ((size_t)(p & 0x1FFFF) << 7) + lo;
        const u16x8 vl = *(const u16x8*)b, vh = *(const u16x8*)(b + 8);
        proc(p, vl, vh);
    }
    while (cur < r1) flush();
}

__global__ __launch_bounds__(512, 6) void fused_rgcn(
    const u16* __restrict__ xb, const u16* __restrict__ WbT,
    const float* __restrict__ bias,
    const int* __restrict__ row_ptr, const int* __restrict__ packed,
    float* __restrict__ out, int N)
{
    __shared__ u16 agg[NPB][LDK];

    const int tid = threadIdx.x;
    const int n0 = blockIdx.x * NPB;
    const int lane = tid & 63;
    const int wv = tid >> 6;
    const int q = lane >> 4, l = lane & 15;
    const int cbase = wv << 4;
    const int grp = tid >> 3;
    const int lo  = (tid & 7) << 4;
    const int gn = n0 + grp;
    u16* arow = &agg[grp][0];
    const float bv = bias[cbase + l];

    f32x4 acc[4] = {};

    #pragma unroll 1
    for (int ck = 0; ck < 3; ++ck) {
        const int r0 = ck * 3;
        const int r1 = (ck == 2) ? 8 : r0 + 3;

        if (gn < N) {
            const int beg = row_ptr[(gn << 3) + r0];
            const int end = row_ptr[(gn << 3) + r1];
            gather8(arow, xb, packed, beg, end, r0, r1, lo);
            if (ck == 2) {
                const u16* sb = xb + ((size_t)gn << 7) + lo;
                *(u16x8*)(arow + 256 + lo)     = *(const u16x8*)sb;
                *(u16x8*)(arow + 256 + lo + 8) = *(const u16x8*)(sb + 8);
            }
        }
        __syncthreads();

        const u16* Bp = WbT + (size_t)(cbase + l) * 1152 + ck * 384 + (q << 3);
        #pragma unroll
        for (int kk = 0; kk < 12; ++kk) {
            const int k0 = (kk << 5) + (q << 3);
            const bf16x8 b = __builtin_bit_cast(bf16x8, *(const u16x8*)(Bp + (kk << 5)));
            #pragma unroll
            for (int mt = 0; mt < 4; ++mt) {
                const bf16x8 a = __builtin_bit_cast(
                    bf16x8, *(const u16x8*)(&agg[(mt << 4) + l][k0]));
                acc[mt] = __builtin_amdgcn_mfma_f32_16x16x32_bf16(a, b, acc[mt], 0, 0, 0);
            }
        }
        if (ck < 2) __syncthreads();
    }

    #pragma unroll
    for (int mt = 0; mt < 4; ++mt) {
        const int rbase = n0 + (mt << 4) + (q << 2);
        #pragma unroll
        for (int j = 0; j < 4; ++j) {
            const int row = rbase + j;
            if (row < N)
                out[(size_t)row * 128 + cbase + l] = fmaxf(acc[mt][j] + bv, 0.f);
        }
    }
}

// ---------- fp32 fallback kernels ----------
__global__ __launch_bounds__(256) void gemm128(
    const float* __restrict__ x, const float* __restrict__ W,
    const float* __restrict__ bias, float* __restrict__ out, int N)
{
    __shared__ float Ws[IN_DIM * OUT_DIM];
    __shared__ float xs[16][IN_DIM];

    const float* Wz = W + (size_t)blockIdx.z * IN_DIM * OUT_DIM;
    float* outz = out + (size_t)blockIdx.z * (size_t)N * OUT_DIM;

    {
        const float4* s4 = (const float4*)Wz;
        float4* d4 = (float4*)Ws;
        for (int i = threadIdx.x; i < IN_DIM * OUT_DIM / 4; i += 256)
            d4[i] = s4[i];
    }

    const int tid = threadIdx.x;
    const int nl = (tid >> 5) * 2;
    const int og = (tid & 31) * 4;

    float4 b4 = make_float4(0.f, 0.f, 0.f, 0.f);
    if (bias) b4 = *(const float4*)&bias[og];

    const int nchunks = (N + 15) / 16;
    for (int chunk = blockIdx.x; chunk < nchunks; chunk += gridDim.x) {
        const int n0 = chunk * 16;
        const int rows = min(16, N - n0);
        __syncthreads();
        {
            const float4* xsrc = (const float4*)(x + (size_t)n0 * IN_DIM);
            float4* xdst = (float4*)&xs[0][0];
            const int n4 = rows * (IN_DIM / 4);
            for (int i = tid; i < n4; i += 256) xdst[i] = xsrc[i];
        }
        __syncthreads();

        if (nl < rows) {
            float a00 = 0.f, a01 = 0.f, a02 = 0.f, a03 = 0.f;
            float a10 = 0.f, a11 = 0.f, a12 = 0.f, a13 = 0.f;
            #pragma unroll 8
            for (int d = 0; d < IN_DIM; ++d) {
                const float4 w4 = *(const float4*)&Ws[d * OUT_DIM + og];
                const float xa = xs[nl][d];
                const float xb = xs[nl + 1][d];
                a00 += xa * w4.x; a01 += xa * w4.y; a02 += xa * w4.z; a03 += xa * w4.w;
                a10 += xb * w4.x; a11 += xb * w4.y; a12 += xb * w4.z; a13 += xb * w4.w;
            }
            float4 r0 = make_float4(a00 + b4.x, a01 + b4.y, a02 + b4.z, a03 + b4.w);
            *(float4*)&outz[(size_t)(n0 + nl) * OUT_DIM + og] = r0;
            if (nl + 1 < rows) {
                float4 r1 = make_float4(a10 + b4.x, a11 + b4.y, a12 + b4.z, a13 + b4.w);
                *(float4*)&outz[(size_t)(n0 + nl + 1) * OUT_DIM + og] = r1;
            }
        }
    }
}

__global__ __launch_bounds__(256) void edge_direct(
    const float* __restrict__ x, const float* __restrict__ W,
    const int* __restrict__ src, const int* __restrict__ dst,
    const int* __restrict__ et, float* __restrict__ out, int E)
{
    long t = (long)blockIdx.x * blockDim.x + threadIdx.x;
    long e = t >> 6;
    int lane = (int)(t & 63);
    if (e >= E) return;
    int s = src[e], d = dst[e], r = et[e];
    const float* xr = x + (long)s * IN_DIM;
    float2 xv = *(const float2*)(xr + lane * 2);
    const float* Wr = W + (long)r * IN_DIM * OUT_DIM;
    const int o0 = lane * 2;
    float a0 = 0.f, a1 = 0.f;
    #pragma unroll 8
    for (int dd = 0; dd < 64; ++dd) {
        float xa = __shfl(xv.x, dd);
        float xb = __shfl(xv.y, dd);
        a0 += xa * Wr[(2 * dd) * OUT_DIM + o0]     + xb * Wr[(2 * dd + 1) * OUT_DIM + o0];
        a1 += xa * Wr[(2 * dd) * OUT_DIM + o0 + 1] + xb * Wr[(2 * dd + 1) * OUT_DIM + o0 + 1];
    }
    atomicAdd(out + (long)d * OUT_DIM + o0, a0);
    atomicAdd(out + (long)d * OUT_DIM + o0 + 1, a1);
}

__global__ __launch_bounds__(256) void relu_k(float* __restrict__ out, long n4)
{
    long i = (long)blockIdx.x * blockDim.x + threadIdx.x;
    if (i >= n4) return;
    float4 v = ((float4*)out)[i];
    v.x = fmaxf(v.x, 0.f); v.y = fmaxf(v.y, 0.f);
    v.z = fmaxf(v.z, 0.f); v.w = fmaxf(v.w, 0.f);
    ((float4*)out)[i] = v;
}

static inline size_t align256(size_t x) { return (x + 255) & ~(size_t)255; }

extern "C" void kernel_launch(void* const* d_in, const int* in_sizes, int n_in,
                              void* d_out, int out_size, void* d_ws, size_t ws_size,
                              hipStream_t stream)
{
    const float* x      = (const float*)d_in[0];
    const float* weight = (const float*)d_in[1];
    const float* slw    = (const float*)d_in[2];
    const float* bias   = (const float*)d_in[3];
    const int*   ei     = (const int*)d_in[4];
    const int*   et     = (const int*)d_in[5];

    const int N = in_sizes[0] / IN_DIM;
    const int E = in_sizes[5];
    const int* src  = ei;
    const int* dstp = ei + E;

    float* out = (float*)d_out;

    const int n8 = N * 8;                      // CSR bins keyed (dst<<3)|rel
    const int ntiles64 = (N + 63) / 64;        // GEMM row tiles (agg padded)

    // workspace layout (cursor..part contiguous -> one k_zero covers both)
    size_t off = 0;
    const size_t xb_off   = off; off += align256((size_t)N * 128 * 2);
    const size_t wb_off   = off; off += align256((size_t)128 * 1152 * 2);
    const size_t rp_off   = off; off += align256((size_t)(n8 + 1) * 4);
    const size_t cur_off  = off; off += align256((size_t)n8 * 4);
    const size_t pt_off   = off; off += align256(256 * 8);
    const size_t pk_off   = off; off += align256((size_t)E * 4);
    const size_t need_core = off;              // enough for the R6 fused path
    const size_t ag_off   = off; off += align256((size_t)ntiles64 * 64 * 1152 * 2);
    const size_t need_split = off;             // + agg for the split path

    const int nchunks = (n8 + 4095) >> 12;   // 4096 elems per scan block

    if (ws_size >= need_core && N <= (1 << 17) && nchunks <= 256) {
        char* base   = (char*)d_ws;
        u16* xb      = (u16*)(base + xb_off);
        u16* WbT     = (u16*)(base + wb_off);
        int* row_ptr = (int*)(base + rp_off);
        int* cursor  = (int*)(base + cur_off);
        unsigned long long* part = (unsigned long long*)(base + pt_off);
        int* packed  = (int*)(base + pk_off);

        // zero cursor + lookback state
        const int n4z = (int)((pk_off - cur_off) / 16);
        k_zero<<<dim3((n4z + 255) / 256), 256, 0, stream>>>(
            (int4*)(base + cur_off), n4z);

        const int BA = (int)(((long)N * 128 / 4 + 255) / 256);
        const int BB = (128 * 1152 / 4 + 255) / 256;   // 144
        const int BD = (E + 255) / 256;
        k_prep<<<dim3(BA + BB + BD), 256, 0, stream>>>(
            x, weight, slw, dstp, et, xb, WbT, cursor, row_ptr, N, E, n8, BA, BB);

        k_scan_lb<<<dim3(nchunks), 512, 0, stream>>>(cursor, row_ptr, cursor, part, n8);
        k_fill<<<dim3((E + 255) / 256), 256, 0, stream>>>(src, dstp, et, cursor, packed, E);

        if (ws_size >= need_split) {
            // barrier-free gather -> agg (L3-resident), then dense MFMA GEMM
            u16* agg = (u16*)(base + ag_off);
            k_gather<<<dim3((N + 15) / 16), 256, 0, stream>>>(
                xb, row_ptr, packed, agg, N);
            k_gemm<<<dim3(ntiles64), 512, 0, stream>>>(agg, WbT, bias, out, N);
        } else {
            // R6 proven fused path (87.6 us)
            fused_rgcn<<<dim3((N + NPB - 1) / NPB), 512, 0, stream>>>(
                xb, WbT, bias, row_ptr, packed, out, N);
        }
    } else if (ws_size >= (size_t)NUM_RELS * N * 128 * 4) {
        gemm128<<<dim3(512, 1, 1), 256, 0, stream>>>(x, slw, bias, out, N);
        long nt = (long)E * 64;
        edge_direct<<<dim3((nt + 255) / 256), 256, 0, stream>>>(x, weight, src, dstp, et, out, E);
        long n4 = (long)N * OUT_DIM / 4;
        relu_k<<<dim3((n4 + 255) / 256), 256, 0, stream>>>(out, n4);
    } else {
        gemm128<<<dim3(512, 1, 1), 256, 0, stream>>>(x, slw, bias, out, N);
        long nt = (long)E * 64;
        edge_direct<<<dim3((nt + 255) / 256), 256, 0, stream>>>(x, weight, src, dstp, et, out, E);
        long n4 = (long)N * OUT_DIM / 4;
        relu_k<<<dim3((n4 + 255) / 256), 256, 0, stream>>>(out, n4);
    }
}

// Round 9
// 270.218 us; speedup vs baseline: 1.3076x; 1.3076x over previous
//
#include <hip/hip_runtime.h>

#define IN_DIM 128
#define OUT_DIM 128
#define NUM_RELS 8

typedef unsigned short u16;
typedef u16 u16x8 __attribute__((ext_vector_type(8)));
typedef u16 u16x4 __attribute__((ext_vector_type(4)));
typedef __bf16 bf16x8 __attribute__((ext_vector_type(8)));
typedef float f32x4 __attribute__((ext_vector_type(4)));

__device__ __forceinline__ u16 f2bf(float f) {
    unsigned u = __float_as_uint(f);
    u += 0x7FFF + ((u >> 16) & 1);      // RNE
    return (u16)(u >> 16);
}
__device__ __forceinline__ float bf2f(u16 h) {
    return __uint_as_float((unsigned)h << 16);
}

// ---------- zero cursor + lookback state ----------
__global__ __launch_bounds__(256) void k_zero(int4* __restrict__ p, int n4)
{
    int i = blockIdx.x * 256 + threadIdx.x;
    if (i < n4) p[i] = make_int4(0, 0, 0, 0);
}

// ---------- prep: cast x -> bf16, build WbT [col][k] (k = rel*128+kin,
// k 1024..1151 = self-loop), (dst,rel) histogram (cursor pre-zeroed) ----------
__global__ __launch_bounds__(256) void k_prep(
    const float* __restrict__ x, const float* __restrict__ weight,
    const float* __restrict__ slw,
    const int* __restrict__ dst, const int* __restrict__ et,
    u16* __restrict__ xb, u16* __restrict__ WbT, int* __restrict__ cursor,
    int* __restrict__ row_ptr,
    int N, int E, int n8, int BA, int BB)
{
    const int b = blockIdx.x;
    const int tid = threadIdx.x;
    if (b == 0 && tid == 0) row_ptr[n8] = E;
    if (b < BA) {
        long i = ((long)b * 256 + tid) * 4;
        if (i < (long)N * 128) {
            float4 v = *(const float4*)(x + i);
            u16x4 o;
            o[0] = f2bf(v.x); o[1] = f2bf(v.y); o[2] = f2bf(v.z); o[3] = f2bf(v.w);
            *(u16x4*)(xb + i) = o;
        }
    } else if (b < BA + BB) {
        int i = ((b - BA) * 256 + tid) * 4;      // elem idx into WbT[128][1152]
        if (i < 128 * 1152) {
            const int col = i / 1152;
            const int kk  = i - col * 1152;
            u16x4 o;
            #pragma unroll
            for (int j = 0; j < 4; ++j) {
                const int kj = kk + j;
                const float f = (kj < 1024)
                    ? weight[((kj >> 7) << 14) + ((kj & 127) << 7) + col]
                    : slw[((kj - 1024) << 7) + col];
                o[j] = f2bf(f);
            }
            *(u16x4*)(WbT + i) = o;
        }
    } else {
        int e = (b - BA - BB) * 256 + tid;
        if (e < E) atomicAdd(&cursor[(dst[e] << 3) + et[e]], 1);
    }
}

// ---------- single-kernel scan: decoupled lookback [verified R5/R6/R8] -------
__global__ __launch_bounds__(512) void k_scan_lb(
    const int* __restrict__ deg, int* __restrict__ row_ptr,
    int* __restrict__ cursor, unsigned long long* __restrict__ part, int n)
{
    __shared__ int s[512];
    __shared__ int s_exc;
    const int c = blockIdx.x;
    const int t = threadIdx.x;
    const int base = (c << 12) + (t << 3);
    int v[8]; int sum = 0;
    #pragma unroll
    for (int j = 0; j < 8; ++j) {
        const int i = base + j;
        v[j] = (i < n) ? deg[i] : 0;
        sum += v[j];
    }
    s[t] = sum;
    __syncthreads();
    #pragma unroll
    for (int off = 1; off < 512; off <<= 1) {
        const int y = (t >= off) ? s[t - off] : 0;
        __syncthreads();
        s[t] += y;
        __syncthreads();
    }
    const int total = s[511];
    const int run = s[t] - sum;

    if (t == 0) {
        const unsigned long long st = (c == 0) ? 2ULL : 1ULL;
        __hip_atomic_store(&part[c], (st << 32) | (unsigned int)total,
                           __ATOMIC_RELAXED, __HIP_MEMORY_SCOPE_AGENT);
    }

    int exc = 0;
    if (c > 0 && t < 64) {
        int bj = c - 1;
        while (true) {
            const int idx = bj - t;
            unsigned long long w = 0;
            if (idx >= 0) {
                do {
                    w = __hip_atomic_load(&part[idx], __ATOMIC_RELAXED,
                                          __HIP_MEMORY_SCOPE_AGENT);
                } while ((w >> 32) == 0ULL);
            }
            const unsigned long long incmask =
                __ballot(idx >= 0 && (w >> 32) == 2ULL);
            const int Ls = incmask ? (__ffsll(incmask) - 1) : 64;
            unsigned int contrib =
                (idx >= 0 && t <= Ls) ? (unsigned int)(w & 0xffffffffULL) : 0u;
            #pragma unroll
            for (int o = 32; o >= 1; o >>= 1) contrib += __shfl_xor(contrib, o);
            exc += (int)contrib;
            if (Ls < 64) break;
            bj -= 64;
        }
        if (t == 0) {
            __hip_atomic_store(&part[c],
                (2ULL << 32) | (unsigned int)(exc + total),
                __ATOMIC_RELAXED, __HIP_MEMORY_SCOPE_AGENT);
            s_exc = exc;
        }
    } else if (t == 0) {
        s_exc = 0;
    }
    __syncthreads();
    exc = s_exc;
    int acc_ = exc + run;
    #pragma unroll
    for (int j = 0; j < 8; ++j) {
        const int i = base + j;
        if (i < n) { row_ptr[i] = acc_; cursor[i] = acc_; }
        acc_ += v[j];
    }
}

__global__ __launch_bounds__(256) void k_fill(
    const int* __restrict__ src, const int* __restrict__ dst,
    const int* __restrict__ et, int* __restrict__ cursor,
    int* __restrict__ packed, int E)
{
    int e = blockIdx.x * blockDim.x + threadIdx.x;
    if (e >= E) return;
    int pos = atomicAdd(&cursor[(dst[e] << 3) + et[e]], 1);
    packed[pos] = (et[e] << 17) | src[e];
}

// ---------- stand-alone gather/aggregate [measured R8: ~47us, as predicted] --
// one 16-lane group per node, ALL 9 rels in one pass, 8 loads in flight/lane,
// fp32 accum + per-rel bf16 flush into agg[*][1152] (L3-resident).
__global__ __launch_bounds__(256, 8) void k_gather(
    const u16* __restrict__ xb,      // [N][128] bf16
    const int* __restrict__ row_ptr, // [8N+1]
    const int* __restrict__ packed,  // [E]: (rel<<17)|src, grouped by (dst,rel)
    u16* __restrict__ agg,           // [>=N][1152] bf16 out
    int N)
{
    const int grp = threadIdx.x >> 4;          // 16 groups/block
    const int lo  = (threadIdx.x & 15) << 3;   // 8 bf16 (16 B) per lane
    const int gn  = blockIdx.x * 16 + grp;
    if (gn >= N) return;

    const int beg = row_ptr[gn << 3];
    const int end = row_ptr[(gn << 3) + 8];
    u16* arow = agg + (size_t)gn * 1152 + lo;

    float a0=0.f,a1=0.f,a2=0.f,a3=0.f,a4=0.f,a5=0.f,a6=0.f,a7=0.f;
    int cur = 0;

#define FLUSH_() { u16x8 o_; \
    o_[0]=f2bf(a0); o_[1]=f2bf(a1); o_[2]=f2bf(a2); o_[3]=f2bf(a3); \
    o_[4]=f2bf(a4); o_[5]=f2bf(a5); o_[6]=f2bf(a6); o_[7]=f2bf(a7); \
    *(u16x8*)(arow + (cur << 7)) = o_; \
    a0=0.f;a1=0.f;a2=0.f;a3=0.f;a4=0.f;a5=0.f;a6=0.f;a7=0.f; ++cur; }

#define PROC_(p_, v_) { const int r_ = (p_) >> 17; \
    while (cur < r_) { FLUSH_(); } \
    a0 += bf2f((v_)[0]); a1 += bf2f((v_)[1]); a2 += bf2f((v_)[2]); a3 += bf2f((v_)[3]); \
    a4 += bf2f((v_)[4]); a5 += bf2f((v_)[5]); a6 += bf2f((v_)[6]); a7 += bf2f((v_)[7]); }

    int k = beg;
    for (; k + 8 <= end; k += 8) {            // 8 independent loads in flight
        const int p0 = packed[k],     p1 = packed[k + 1];
        const int p2 = packed[k + 2], p3 = packed[k + 3];
        const int p4 = packed[k + 4], p5 = packed[k + 5];
        const int p6 = packed[k + 6], p7 = packed[k + 7];
        const u16x8 v0 = *(const u16x8*)(xb + ((size_t)(p0 & 0x1FFFF) << 7) + lo);
        const u16x8 v1 = *(const u16x8*)(xb + ((size_t)(p1 & 0x1FFFF) << 7) + lo);
        const u16x8 v2 = *(const u16x8*)(xb + ((size_t)(p2 & 0x1FFFF) << 7) + lo);
        const u16x8 v3 = *(const u16x8*)(xb + ((size_t)(p3 & 0x1FFFF) << 7) + lo);
        const u16x8 v4 = *(const u16x8*)(xb + ((size_t)(p4 & 0x1FFFF) << 7) + lo);
        const u16x8 v5 = *(const u16x8*)(xb + ((size_t)(p5 & 0x1FFFF) << 7) + lo);
        const u16x8 v6 = *(const u16x8*)(xb + ((size_t)(p6 & 0x1FFFF) << 7) + lo);
        const u16x8 v7 = *(const u16x8*)(xb + ((size_t)(p7 & 0x1FFFF) << 7) + lo);
        PROC_(p0, v0); PROC_(p1, v1); PROC_(p2, v2); PROC_(p3, v3);
        PROC_(p4, v4); PROC_(p5, v5); PROC_(p6, v6); PROC_(p7, v7);
    }
    for (; k + 4 <= end; k += 4) {
        const int p0 = packed[k],     p1 = packed[k + 1];
        const int p2 = packed[k + 2], p3 = packed[k + 3];
        const u16x8 v0 = *(const u16x8*)(xb + ((size_t)(p0 & 0x1FFFF) << 7) + lo);
        const u16x8 v1 = *(const u16x8*)(xb + ((size_t)(p1 & 0x1FFFF) << 7) + lo);
        const u16x8 v2 = *(const u16x8*)(xb + ((size_t)(p2 & 0x1FFFF) << 7) + lo);
        const u16x8 v3 = *(const u16x8*)(xb + ((size_t)(p3 & 0x1FFFF) << 7) + lo);
        PROC_(p0, v0); PROC_(p1, v1); PROC_(p2, v2); PROC_(p3, v3);
    }
    for (; k < end; ++k) {
        const int p = packed[k];
        const u16x8 v = *(const u16x8*)(xb + ((size_t)(p & 0x1FFFF) << 7) + lo);
        PROC_(p, v);
    }
    while (cur < 8) { FLUSH_(); }             // empty rels -> explicit zeros
#undef PROC_
#undef FLUSH_

    // self-loop slot (k 1024..1151) = xb row verbatim
    *(u16x8*)(arow + 1024) = *(const u16x8*)(xb + ((size_t)gn << 7) + lo);
}

// ---------- R9: k_gemm rebuilt on the mfma_gemm2-PROVEN register structure --
// [R8 post-mortem: old k_gemm = 166us, VGPR 24, MfmaUtil 3.4% — 64x16/wave
//  with B reloaded per kk left zero ILP; compiler serialized one load at a
//  time. mfma_gemm2 (R0, frozen) did the SAME 14.75 GF in 41us while also
//  writing 112 MB: B-frags resident in 64 VGPRs, wave owns 64x64 (acc[4][4]),
//  16 independent A-loads in flight per kc.]
// One block per 128-row tile, 256 thr / 4 waves. Loop kb over 9 K-chunks of
// 128: Bf[4][4] loaded as CONTIGUOUS u16x8 from WbT[col][k] (col-major ->
// vectorized, improves on R0's scalar B loads), inner kc: 4 A-loads (16 B,
// stride 2304) + 16 MFMAs. A from L3-resident agg, B L2-hot. bias+relu out.
__global__ __launch_bounds__(256, 2) void k_gemm(
    const u16* __restrict__ agg,     // [>=ntiles128*128][1152] bf16
    const u16* __restrict__ WbT,     // [128][1152] bf16
    const float* __restrict__ bias,
    float* __restrict__ out, int N)
{
    const int tid = threadIdx.x;
    const int lane = tid & 63, wv = tid >> 6;
    const int q = lane >> 4, l = lane & 15;
    const int mbase = (wv >> 1) << 6;   // 0 | 64
    const int cbase = (wv & 1) << 6;    // 0 | 64
    const int n0 = blockIdx.x * 128;

    f32x4 acc[4][4] = {};

    #pragma unroll 1
    for (int kb = 0; kb < 9; ++kb) {
        const int kbase = kb << 7;

        u16x8 Bf[4][4];
        #pragma unroll
        for (int nt = 0; nt < 4; ++nt) {
            const u16* bp = WbT + (size_t)(cbase + (nt << 4) + l) * 1152
                                + kbase + (q << 3);
            #pragma unroll
            for (int kc = 0; kc < 4; ++kc)
                Bf[nt][kc] = *(const u16x8*)(bp + (kc << 5));
        }

        #pragma unroll
        for (int kc = 0; kc < 4; ++kc) {
            const int ko = kbase + (kc << 5) + (q << 3);
            u16x8 a[4];
            #pragma unroll
            for (int mt = 0; mt < 4; ++mt) {
                const int row = n0 + mbase + (mt << 4) + l;
                a[mt] = *(const u16x8*)(agg + (size_t)row * 1152 + ko);
            }
            #pragma unroll
            for (int nt = 0; nt < 4; ++nt) {
                const bf16x8 b = __builtin_bit_cast(bf16x8, Bf[nt][kc]);
                #pragma unroll
                for (int mt = 0; mt < 4; ++mt) {
                    acc[mt][nt] = __builtin_amdgcn_mfma_f32_16x16x32_bf16(
                        __builtin_bit_cast(bf16x8, a[mt]), b, acc[mt][nt], 0, 0, 0);
                }
            }
        }
    }

    // epilogue: C layout col=lane&15, row=(lane>>4)*4+j; +bias, relu, fp32 out
    #pragma unroll
    for (int nt = 0; nt < 4; ++nt) {
        const int col = cbase + (nt << 4) + l;
        const float bv = bias[col];
        #pragma unroll
        for (int mt = 0; mt < 4; ++mt) {
            const int rbase = n0 + mbase + (mt << 4) + (q << 2);
            #pragma unroll
            for (int j = 0; j < 4; ++j) {
                const int row = rbase + j;
                if (row < N)
                    out[(size_t)row * 128 + col] = fmaxf(acc[mt][nt][j] + bv, 0.f);
            }
        }
    }
}

// ---------- R6 fused kernel (fallback if agg buffer doesn't fit) ----------
#define NPB 64
#define LDK 392

__device__ __forceinline__ void gather8(
    u16* arow, const u16* __restrict__ xb, const int* __restrict__ packed,
    int beg, int end, int r0, int r1, int lo)
{
    float a[16];
    #pragma unroll
    for (int j = 0; j < 16; ++j) a[j] = 0.f;
    int cur = r0;

    auto flush = [&]() {
        u16x8 ol, oh;
        #pragma unroll
        for (int j = 0; j < 8; ++j) {
            ol[j] = f2bf(a[j]);     a[j] = 0.f;
            oh[j] = f2bf(a[8 + j]); a[8 + j] = 0.f;
        }
        u16* p = arow + ((cur - r0) << 7) + lo;
        *(u16x8*)p = ol;
        *(u16x8*)(p + 8) = oh;
        ++cur;
    };
    auto proc = [&](int p, const u16x8& vl, const u16x8& vh) {
        const int r_ = p >> 17;
        while (cur < r_) flush();
        #pragma unroll
        for (int j = 0; j < 8; ++j) {
            a[j]     += bf2f(vl[j]);
            a[8 + j] += bf2f(vh[j]);
        }
    };

    int k = beg;
    for (; k + 4 <= end; k += 4) {
        const int p0 = packed[k],     p1 = packed[k + 1];
        const int p2 = packed[k + 2], p3 = packed[k + 3];
        const u16* b0 = xb + ((size_t)(p0 & 0x1FFFF) << 7) + lo;
        const u16* b1 = xb + ((size_t)(p1 & 0x1FFFF) << 7) + lo;
        const u16* b2 = xb + ((size_t)(p2 & 0x1FFFF) << 7) + lo;
        const u16* b3 = xb + ((size_t)(p3 & 0x1FFFF) << 7) + lo;
        const u16x8 v0l = *(const u16x8*)b0, v0h = *(const u16x8*)(b0 + 8);
        const u16x8 v1l = *(const u16x8*)b1, v1h = *(const u16x8*)(b1 + 8);
        const u16x8 v2l = *(const u16x8*)b2, v2h = *(const u16x8*)(b2 + 8);
        const u16x8 v3l = *(const u16x8*)b3, v3h = *(const u16x8*)(b3 + 8);
        proc(p0, v0l, v0h); proc(p1, v1l, v1h);
        proc(p2, v2l, v2h); proc(p3, v3l, v3h);
    }
    for (; k < end; ++k) {
        const int p = packed[k];
        const u16* b = xb + ((size_t)(p & 0x1FFFF) << 7) + lo;
        const u16x8 vl = *(const u16x8*)b, vh = *(const u16x8*)(b + 8);
        proc(p, vl, vh);
    }
    while (cur < r1) flush();
}

__global__ __launch_bounds__(512, 6) void fused_rgcn(
    const u16* __restrict__ xb, const u16* __restrict__ WbT,
    const float* __restrict__ bias,
    const int* __restrict__ row_ptr, const int* __restrict__ packed,
    float* __restrict__ out, int N)
{
    __shared__ u16 agg[NPB][LDK];

    const int tid = threadIdx.x;
    const int n0 = blockIdx.x * NPB;
    const int lane = tid & 63;
    const int wv = tid >> 6;
    const int q = lane >> 4, l = lane & 15;
    const int cbase = wv << 4;
    const int grp = tid >> 3;
    const int lo  = (tid & 7) << 4;
    const int gn = n0 + grp;
    u16* arow = &agg[grp][0];
    const float bv = bias[cbase + l];

    f32x4 acc[4] = {};

    #pragma unroll 1
    for (int ck = 0; ck < 3; ++ck) {
        const int r0 = ck * 3;
        const int r1 = (ck == 2) ? 8 : r0 + 3;

        if (gn < N) {
            const int beg = row_ptr[(gn << 3) + r0];
            const int end = row_ptr[(gn << 3) + r1];
            gather8(arow, xb, packed, beg, end, r0, r1, lo);
            if (ck == 2) {
                const u16* sb = xb + ((size_t)gn << 7) + lo;
                *(u16x8*)(arow + 256 + lo)     = *(const u16x8*)sb;
                *(u16x8*)(arow + 256 + lo + 8) = *(const u16x8*)(sb + 8);
            }
        }
        __syncthreads();

        const u16* Bp = WbT + (size_t)(cbase + l) * 1152 + ck * 384 + (q << 3);
        #pragma unroll
        for (int kk = 0; kk < 12; ++kk) {
            const int k0 = (kk << 5) + (q << 3);
            const bf16x8 b = __builtin_bit_cast(bf16x8, *(const u16x8*)(Bp + (kk << 5)));
            #pragma unroll
            for (int mt = 0; mt < 4; ++mt) {
                const bf16x8 a = __builtin_bit_cast(
                    bf16x8, *(const u16x8*)(&agg[(mt << 4) + l][k0]));
                acc[mt] = __builtin_amdgcn_mfma_f32_16x16x32_bf16(a, b, acc[mt], 0, 0, 0);
            }
        }
        if (ck < 2) __syncthreads();
    }

    #pragma unroll
    for (int mt = 0; mt < 4; ++mt) {
        const int rbase = n0 + (mt << 4) + (q << 2);
        #pragma unroll
        for (int j = 0; j < 4; ++j) {
            const int row = rbase + j;
            if (row < N)
                out[(size_t)row * 128 + cbase + l] = fmaxf(acc[mt][j] + bv, 0.f);
        }
    }
}

// ---------- fp32 fallback kernels ----------
__global__ __launch_bounds__(256) void gemm128(
    const float* __restrict__ x, const float* __restrict__ W,
    const float* __restrict__ bias, float* __restrict__ out, int N)
{
    __shared__ float Ws[IN_DIM * OUT_DIM];
    __shared__ float xs[16][IN_DIM];

    const float* Wz = W + (size_t)blockIdx.z * IN_DIM * OUT_DIM;
    float* outz = out + (size_t)blockIdx.z * (size_t)N * OUT_DIM;

    {
        const float4* s4 = (const float4*)Wz;
        float4* d4 = (float4*)Ws;
        for (int i = threadIdx.x; i < IN_DIM * OUT_DIM / 4; i += 256)
            d4[i] = s4[i];
    }

    const int tid = threadIdx.x;
    const int nl = (tid >> 5) * 2;
    const int og = (tid & 31) * 4;

    float4 b4 = make_float4(0.f, 0.f, 0.f, 0.f);
    if (bias) b4 = *(const float4*)&bias[og];

    const int nchunks = (N + 15) / 16;
    for (int chunk = blockIdx.x; chunk < nchunks; chunk += gridDim.x) {
        const int n0 = chunk * 16;
        const int rows = min(16, N - n0);
        __syncthreads();
        {
            const float4* xsrc = (const float4*)(x + (size_t)n0 * IN_DIM);
            float4* xdst = (float4*)&xs[0][0];
            const int n4 = rows * (IN_DIM / 4);
            for (int i = tid; i < n4; i += 256) xdst[i] = xsrc[i];
        }
        __syncthreads();

        if (nl < rows) {
            float a00 = 0.f, a01 = 0.f, a02 = 0.f, a03 = 0.f;
            float a10 = 0.f, a11 = 0.f, a12 = 0.f, a13 = 0.f;
            #pragma unroll 8
            for (int d = 0; d < IN_DIM; ++d) {
                const float4 w4 = *(const float4*)&Ws[d * OUT_DIM + og];
                const float xa = xs[nl][d];
                const float xb = xs[nl + 1][d];
                a00 += xa * w4.x; a01 += xa * w4.y; a02 += xa * w4.z; a03 += xa * w4.w;
                a10 += xb * w4.x; a11 += xb * w4.y; a12 += xb * w4.z; a13 += xb * w4.w;
            }
            float4 r0 = make_float4(a00 + b4.x, a01 + b4.y, a02 + b4.z, a03 + b4.w);
            *(float4*)&outz[(size_t)(n0 + nl) * OUT_DIM + og] = r0;
            if (nl + 1 < rows) {
                float4 r1 = make_float4(a10 + b4.x, a11 + b4.y, a12 + b4.z, a13 + b4.w);
                *(float4*)&outz[(size_t)(n0 + nl + 1) * OUT_DIM + og] = r1;
            }
        }
    }
}

__global__ __launch_bounds__(256) void edge_direct(
    const float* __restrict__ x, const float* __restrict__ W,
    const int* __restrict__ src, const int* __restrict__ dst,
    const int* __restrict__ et, float* __restrict__ out, int E)
{
    long t = (long)blockIdx.x * blockDim.x + threadIdx.x;
    long e = t >> 6;
    int lane = (int)(t & 63);
    if (e >= E) return;
    int s = src[e], d = dst[e], r = et[e];
    const float* xr = x + (long)s * IN_DIM;
    float2 xv = *(const float2*)(xr + lane * 2);
    const float* Wr = W + (long)r * IN_DIM * OUT_DIM;
    const int o0 = lane * 2;
    float a0 = 0.f, a1 = 0.f;
    #pragma unroll 8
    for (int dd = 0; dd < 64; ++dd) {
        float xa = __shfl(xv.x, dd);
        float xb = __shfl(xv.y, dd);
        a0 += xa * Wr[(2 * dd) * OUT_DIM + o0]     + xb * Wr[(2 * dd + 1) * OUT_DIM + o0];
        a1 += xa * Wr[(2 * dd) * OUT_DIM + o0 + 1] + xb * Wr[(2 * dd + 1) * OUT_DIM + o0 + 1];
    }
    atomicAdd(out + (long)d * OUT_DIM + o0, a0);
    atomicAdd(out + (long)d * OUT_DIM + o0 + 1, a1);
}

__global__ __launch_bounds__(256) void relu_k(float* __restrict__ out, long n4)
{
    long i = (long)blockIdx.x * blockDim.x + threadIdx.x;
    if (i >= n4) return;
    float4 v = ((float4*)out)[i];
    v.x = fmaxf(v.x, 0.f); v.y = fmaxf(v.y, 0.f);
    v.z = fmaxf(v.z, 0.f); v.w = fmaxf(v.w, 0.f);
    ((float4*)out)[i] = v;
}

static inline size_t align256(size_t x) { return (x + 255) & ~(size_t)255; }

extern "C" void kernel_launch(void* const* d_in, const int* in_sizes, int n_in,
                              void* d_out, int out_size, void* d_ws, size_t ws_size,
                              hipStream_t stream)
{
    const float* x      = (const float*)d_in[0];
    const float* weight = (const float*)d_in[1];
    const float* slw    = (const float*)d_in[2];
    const float* bias   = (const float*)d_in[3];
    const int*   ei     = (const int*)d_in[4];
    const int*   et     = (const int*)d_in[5];

    const int N = in_sizes[0] / IN_DIM;
    const int E = in_sizes[5];
    const int* src  = ei;
    const int* dstp = ei + E;

    float* out = (float*)d_out;

    const int n8 = N * 8;                        // CSR bins keyed (dst<<3)|rel
    const int ntiles128 = (N + 127) / 128;       // GEMM row tiles (agg padded)

    // workspace layout (cursor..part contiguous -> one k_zero covers both)
    size_t off = 0;
    const size_t xb_off   = off; off += align256((size_t)N * 128 * 2);
    const size_t wb_off   = off; off += align256((size_t)128 * 1152 * 2);
    const size_t rp_off   = off; off += align256((size_t)(n8 + 1) * 4);
    const size_t cur_off  = off; off += align256((size_t)n8 * 4);
    const size_t pt_off   = off; off += align256(256 * 8);
    const size_t pk_off   = off; off += align256((size_t)E * 4);
    const size_t need_core = off;                // enough for the R6 fused path
    const size_t ag_off   = off; off += align256((size_t)ntiles128 * 128 * 1152 * 2);
    const size_t need_split = off;               // + agg for the split path

    const int nchunks = (n8 + 4095) >> 12;   // 4096 elems per scan block

    if (ws_size >= need_core && N <= (1 << 17) && nchunks <= 256) {
        char* base   = (char*)d_ws;
        u16* xb      = (u16*)(base + xb_off);
        u16* WbT     = (u16*)(base + wb_off);
        int* row_ptr = (int*)(base + rp_off);
        int* cursor  = (int*)(base + cur_off);
        unsigned long long* part = (unsigned long long*)(base + pt_off);
        int* packed  = (int*)(base + pk_off);

        // zero cursor + lookback state
        const int n4z = (int)((pk_off - cur_off) / 16);
        k_zero<<<dim3((n4z + 255) / 256), 256, 0, stream>>>(
            (int4*)(base + cur_off), n4z);

        const int BA = (int)(((long)N * 128 / 4 + 255) / 256);
        const int BB = (128 * 1152 / 4 + 255) / 256;   // 144
        const int BD = (E + 255) / 256;
        k_prep<<<dim3(BA + BB + BD), 256, 0, stream>>>(
            x, weight, slw, dstp, et, xb, WbT, cursor, row_ptr, N, E, n8, BA, BB);

        k_scan_lb<<<dim3(nchunks), 512, 0, stream>>>(cursor, row_ptr, cursor, part, n8);
        k_fill<<<dim3((E + 255) / 256), 256, 0, stream>>>(src, dstp, et, cursor, packed, E);

        if (ws_size >= need_split) {
            // barrier-free gather -> agg (L3-resident), then dense MFMA GEMM
            u16* agg = (u16*)(base + ag_off);
            k_gather<<<dim3((N + 15) / 16), 256, 0, stream>>>(
                xb, row_ptr, packed, agg, N);
            k_gemm<<<dim3(ntiles128), 256, 0, stream>>>(agg, WbT, bias, out, N);
        } else {
            // R6 proven fused path (87.6 us)
            fused_rgcn<<<dim3((N + NPB - 1) / NPB), 512, 0, stream>>>(
                xb, WbT, bias, row_ptr, packed, out, N);
        }
    } else if (ws_size >= (size_t)NUM_RELS * N * 128 * 4) {
        gemm128<<<dim3(512, 1, 1), 256, 0, stream>>>(x, slw, bias, out, N);
        long nt = (long)E * 64;
        edge_direct<<<dim3((nt + 255) / 256), 256, 0, stream>>>(x, weight, src, dstp, et, out, E);
        long n4 = (long)N * OUT_DIM / 4;
        relu_k<<<dim3((n4 + 255) / 256), 256, 0, stream>>>(out, n4);
    } else {
        gemm128<<<dim3(512, 1, 1), 256, 0, stream>>>(x, slw, bias, out, N);
        long nt = (long)E * 64;
        edge_direct<<<dim3((nt + 255) / 256), 256, 0, stream>>>(x, weight, src, dstp, et, out, E);
        long n4 = (long)N * OUT_DIM / 4;
        relu_k<<<dim3((n4 + 255) / 256), 256, 0, stream>>>(out, n4);
    }
}